// Round 11
// baseline (679.361 us; speedup 1.0000x reference)
//
#include <hip/hip_runtime.h>

#define DD 32
#define HH 8
#define ALPHA 0.01f
#define SCAN_T 256
#define SCAN_E 1024       // elements scanned per block (4 per thread)

__global__ __launch_bounds__(256) void k_zero(int* __restrict__ cnt, int N) {
    int i = blockIdx.x * 256 + threadIdx.x;
    if (i < N) cnt[i] = 0;
}

__global__ __launch_bounds__(256) void k_count(const int* __restrict__ dst, int E,
                                               int* __restrict__ cnt) {
    int e = blockIdx.x * 256 + threadIdx.x;
    if (e < E) atomicAdd(&cnt[dst[e]], 1);
}

// per-block sums of cnt (SCAN_E elements per block)
__global__ __launch_bounds__(SCAN_T) void k_scan1(const int* __restrict__ cnt, int N,
                                                  int* __restrict__ bsum) {
    __shared__ int sh[SCAN_T];
    int t = threadIdx.x, b = blockIdx.x;
    int base = b * SCAN_E + t * 4;
    int s = 0;
    #pragma unroll
    for (int k = 0; k < 4; k++) { int i = base + k; if (i < N) s += cnt[i]; }
    sh[t] = s; __syncthreads();
    for (int off = SCAN_T / 2; off > 0; off >>= 1) {
        if (t < off) sh[t] += sh[t + off];
        __syncthreads();
    }
    if (t == 0) bsum[b] = sh[0];
}

// exclusive scan of block sums (nb <= SCAN_T), single block
__global__ __launch_bounds__(SCAN_T) void k_scan2(const int* __restrict__ bsum, int nb,
                                                  int* __restrict__ boff) {
    __shared__ int sh[SCAN_T];
    int t = threadIdx.x;
    int x = (t < nb) ? bsum[t] : 0;
    sh[t] = x; __syncthreads();
    for (int off = 1; off < SCAN_T; off <<= 1) {
        int v = (t >= off) ? sh[t - off] : 0;
        __syncthreads();
        sh[t] += v;
        __syncthreads();
    }
    if (t < nb) boff[t] = sh[t] - x;   // exclusive
}

// exclusive scan within each block + boff -> row_ptr
__global__ __launch_bounds__(SCAN_T) void k_scan3(const int* __restrict__ cnt, int N, int E,
                                                  const int* __restrict__ boff,
                                                  int* __restrict__ row_ptr) {
    __shared__ int sh[SCAN_T];
    int t = threadIdx.x, b = blockIdx.x;
    int base = b * SCAN_E + t * 4;
    int c[4];
    #pragma unroll
    for (int k = 0; k < 4; k++) { int i = base + k; c[k] = (i < N) ? cnt[i] : 0; }
    int ts = c[0] + c[1] + c[2] + c[3];
    sh[t] = ts; __syncthreads();
    for (int off = 1; off < SCAN_T; off <<= 1) {
        int v = (t >= off) ? sh[t - off] : 0;
        __syncthreads();
        sh[t] += v;
        __syncthreads();
    }
    int rp = boff[b] + sh[t] - ts;      // exclusive prefix for this thread's 4 elems
    int acc = 0;
    #pragma unroll
    for (int k = 0; k < 4; k++) {
        int i = base + k;
        if (i < N) row_ptr[i] = rp + acc;
        acc += c[k];
    }
    if (b == 0 && t == 0) row_ptr[N] = E;
}

// scatter edge ids into CSR buckets (cnt counts down to 0)
__global__ __launch_bounds__(256) void k_fill(const int* __restrict__ dst, int E,
                                              const int* __restrict__ row_ptr,
                                              int* __restrict__ cnt, int* __restrict__ eid) {
    int e = blockIdx.x * 256 + threadIdx.x;
    if (e >= E) return;
    int n = dst[e];
    int r = atomicAdd(&cnt[n], -1) - 1;   // unique cursor in [0, deg)
    eid[row_ptr[n] + r] = e;
}

// Fused encode + softmax + aggregate. One wave per node; two edges in flight
// (one per 32-lane half). Lane d of each half holds dim d. l2norms and
// h.attn_q dots via width-32 shfl_xor butterflies. Accumulates numerator and
// denominator in registers (out = sum(ex*h)/sum(ex)); no intermediates,
// no atomics, one coalesced 1KB output write per node.
__global__ __launch_bounds__(256) void k_fused(
    const float* __restrict__ f0, const float* __restrict__ f1, const float* __restrict__ f2,
    const float* __restrict__ rv, const float* __restrict__ attn,
    const int* __restrict__ row_ptr, const int* __restrict__ eid,
    float* __restrict__ out, int N)
{
    int wid = threadIdx.x >> 6, lane = threadIdx.x & 63;
    int n = blockIdx.x * 4 + wid;
    if (n >= N) return;
    int d = lane & 31;
    int hq = lane >> 5;                       // half id: processes edges j+hq

    // per-lane constants (L1-cached broadcast reads)
    float att_q[HH];
    #pragma unroll
    for (int q = 0; q < HH; q++) att_q[q] = attn[q * DD + d];
    float Rd = rv[d] + 2.0f * (rv[DD + d] + rv[2 * DD + d]);

    int r0 = row_ptr[n], r1 = row_ptr[n + 1];
    int deg = r1 - r0;

    float num[HH], den[HH];
    #pragma unroll
    for (int q = 0; q < HH; q++) { num[q] = 0.f; den[q] = 0.f; }

    for (int j = 0; j < deg; j += 2) {
        int idx = j + hq;
        bool valid = idx < deg;
        int e = eid[r0 + (valid ? idx : 0)];  // clamp: reads a real edge, contribution zeroed
        size_t off = (size_t)e * DD + d;
        float x0 = f0[off], x1 = f1[off], x2 = f2[off];   // 3 x 128B full-line gathers

        float s0 = x0 * x0, s1 = x1 * x1, s2 = x2 * x2;
        #pragma unroll
        for (int o = 16; o >= 1; o >>= 1) {
            s0 += __shfl_xor(s0, o, 32);
            s1 += __shfl_xor(s1, o, 32);
            s2 += __shfl_xor(s2, o, 32);
        }
        float i0 = 1.0f / fmaxf(sqrtf(s0), 1e-12f);
        float i1 = 1.0f / fmaxf(sqrtf(s1), 1e-12f);
        float i2 = 1.0f / fmaxf(sqrtf(s2), 1e-12f);
        float h = (x0 * i0 + x1 * i1 + x2 * i2 + Rd) * (1.0f / 3.0f);

        float ex[HH];
        #pragma unroll
        for (int q = 0; q < HH; q++) {
            float p = h * att_q[q];
            #pragma unroll
            for (int o = 16; o >= 1; o >>= 1) p += __shfl_xor(p, o, 32);
            float a = p > 0.f ? p : ALPHA * p;
            ex[q] = valid ? __expf(a) : 0.f;
        }
        float hv = valid ? h : 0.f;
        #pragma unroll
        for (int q = 0; q < HH; q++) { den[q] += ex[q]; num[q] += ex[q] * hv; }
    }

    // combine the two halves (even-edge + odd-edge partials)
    #pragma unroll
    for (int q = 0; q < HH; q++) {
        num[q] += __shfl_xor(num[q], 32, 64);
        den[q] += __shfl_xor(den[q], 32, 64);
    }

    size_t ob = (size_t)n * (HH * DD);
    #pragma unroll
    for (int k = 0; k < 4; k++) {
        int q = hq * 4 + k;                   // half0 writes heads 0-3, half1 heads 4-7
        float dv = den[q];
        float rr = dv > 0.f ? 1.0f / dv : 0.f;
        out[ob + (size_t)q * DD + d] = num[q] * rr;
    }
}

extern "C" void kernel_launch(void* const* d_in, const int* in_sizes, int n_in,
                              void* d_out, int out_size, void* d_ws, size_t ws_size,
                              hipStream_t stream)
{
    const float* f0   = (const float*)d_in[0];
    const float* f1   = (const float*)d_in[1];
    const float* f2   = (const float*)d_in[2];
    const float* rv   = (const float*)d_in[3];
    const float* attn = (const float*)d_in[4];
    const int*   dst  = (const int*)d_in[5];
    int E = in_sizes[0] / DD;
    int N = out_size / (HH * DD);
    float* out = (float*)d_out;

    auto al = [](size_t x) { return (x + 255) & ~(size_t)255; };
    char* w = (char*)d_ws;
    size_t off = 0;
    int* eid     = (int*)(w + off); off += al((size_t)E * 4);
    int* row_ptr = (int*)(w + off); off += al(((size_t)N + 1) * 4);
    int* cnt     = (int*)(w + off); off += al((size_t)N * 4);
    int* bsum    = (int*)(w + off); off += al((size_t)SCAN_T * 4);
    int* boff    = (int*)(w + off); off += al((size_t)SCAN_T * 4);
    (void)ws_size; (void)n_in;

    int nb = (N + SCAN_E - 1) / SCAN_E;      // 98 for N=100k (must be <= SCAN_T)
    int gridE = (E + 255) / 256;

    k_zero<<<(N + 255) / 256, 256, 0, stream>>>(cnt, N);
    k_count<<<gridE, 256, 0, stream>>>(dst, E, cnt);
    k_scan1<<<nb, SCAN_T, 0, stream>>>(cnt, N, bsum);
    k_scan2<<<1, SCAN_T, 0, stream>>>(bsum, nb, boff);
    k_scan3<<<nb, SCAN_T, 0, stream>>>(cnt, N, E, boff, row_ptr);
    k_fill<<<gridE, 256, 0, stream>>>(dst, E, row_ptr, cnt, eid);
    k_fused<<<(N + 3) / 4, 256, 0, stream>>>(f0, f1, f2, rv, attn, row_ptr, eid, out, N);
}

// Round 15
// 524.746 us; speedup vs baseline: 1.2946x; 1.2946x over previous
//
#include <hip/hip_runtime.h>

#define DD 32
#define HH 8
#define ALPHA 0.01f
#define CAP 32            // slots per node; overflow handled exactly via ovf list
#define G 16              // nodes per block
#define ECH 256           // edge slots encoded per chunk (== blockDim)
#define LST 44            // LDS dwords per edge slot: 32 h + 8 ex + pad (16B aligned)
#define OVF_MAX (1 << 20)

__global__ __launch_bounds__(256) void k_zero(int* __restrict__ cnt, int* __restrict__ ovfc, int N) {
    int i = blockIdx.x * 256 + threadIdx.x;
    if (i < N) cnt[i] = 0;
    if (i == 0) *ovfc = 0;
}

// one atomic per edge; slot array holds edge ids only (4B)
__global__ __launch_bounds__(256) void k_slot(const int* __restrict__ dst, int E,
                                              int* __restrict__ cnt, int* __restrict__ slots,
                                              int* __restrict__ ovfc, int2* __restrict__ ovf) {
    int e = blockIdx.x * 256 + threadIdx.x;
    if (e >= E) return;
    int n = dst[e];
    int r = atomicAdd(&cnt[n], 1);
    if (r < CAP) slots[(size_t)n * CAP + r] = e;
    else { int k = atomicAdd(ovfc, 1); if (k < OVF_MAX) ovf[k] = make_int2(e, n); }
}

// rare-path full encode for one edge (returns h[d] and ex[8]); never runs for Poisson(10) degs
__device__ __noinline__ void ovf_encode(const float* __restrict__ f0, const float* __restrict__ f1,
                                        const float* __restrict__ f2, const float* __restrict__ s_R,
                                        const float* __restrict__ s_att, int e, int d,
                                        float* hd, float* ex) {
    float h[DD];
    float s0 = 0.f, s1 = 0.f, s2 = 0.f;
    for (int i = 0; i < DD; i++) {
        float x0 = f0[(size_t)e * DD + i], x1 = f1[(size_t)e * DD + i], x2 = f2[(size_t)e * DD + i];
        s0 += x0 * x0; s1 += x1 * x1; s2 += x2 * x2;
        h[i] = x0; // stash
    }
    float i0 = 1.0f / fmaxf(sqrtf(s0), 1e-12f);
    float i1 = 1.0f / fmaxf(sqrtf(s1), 1e-12f);
    float i2 = 1.0f / fmaxf(sqrtf(s2), 1e-12f);
    for (int i = 0; i < DD; i++) {
        float x1 = f1[(size_t)e * DD + i], x2 = f2[(size_t)e * DD + i];
        h[i] = (h[i] * i0 + x1 * i1 + x2 * i2 + s_R[i]) * (1.0f / 3.0f);
    }
    for (int q = 0; q < HH; q++) {
        float a = 0.f;
        for (int i = 0; i < DD; i++) a += h[i] * s_att[q * DD + i];
        a = a > 0.f ? a : ALPHA * a;
        ex[q] = __expf(a);
    }
    *hd = h[d];
}

// Fused encode+aggregate. Block = 16 nodes. Phase 1: thread-per-edge encode into
// LDS (no cross-lane redundancy). Phase 2: thread (node,dim) accumulates num/den
// from LDS (broadcast ex reads, conflict-free h reads). One coalesced out write.
__global__ __launch_bounds__(256) void k_fused(
    const float* __restrict__ f0, const float* __restrict__ f1, const float* __restrict__ f2,
    const float* __restrict__ rv, const float* __restrict__ attn,
    const int* __restrict__ slots, const int* __restrict__ cnt,
    const int* __restrict__ ovfc, const int2* __restrict__ ovf,
    float* __restrict__ out, int N)
{
    __shared__ float s_att[HH * DD];          // [q*32+d]
    __shared__ float s_R[DD];
    __shared__ float s_edge[ECH * LST];       // 45056 B
    __shared__ int s_p[G + 1];
    __shared__ int s_rawdeg[G];

    int t = threadIdx.x;
    s_att[t] = attn[t];                       // blockDim == HH*DD == 256
    if (t < DD) s_R[t] = rv[t] + 2.0f * (rv[DD + t] + rv[2 * DD + t]);
    int b0 = blockIdx.x * G;
    if (t < G) {
        int n = b0 + t;
        s_rawdeg[t] = (n < N) ? cnt[n] : 0;
    }
    __syncthreads();
    if (t == 0) {
        int a = 0;
        for (int i = 0; i < G; i++) {
            s_p[i] = a;
            int dg = s_rawdeg[i];
            a += (dg < CAP ? dg : CAP);
        }
        s_p[G] = a;
    }
    __syncthreads();
    int total = s_p[G];                       // <= G*CAP = 512 -> at most 2 chunks

    int d = t & 31, nl0 = t >> 5;             // this thread owns (node nl0, dim d) and (node nl0+8, dim d)
    float num0[HH], den0[HH], num1[HH], den1[HH];
    #pragma unroll
    for (int q = 0; q < HH; q++) { num0[q] = den0[q] = num1[q] = den1[q] = 0.f; }

    for (int base = 0; base < total; base += ECH) {
        int idx = base + t;
        if (idx < total) {
            // locate (node, j) by binary search over 16-entry prefix
            int nl = 0;
            if (idx >= s_p[nl + 8]) nl += 8;
            if (idx >= s_p[nl + 4]) nl += 4;
            if (idx >= s_p[nl + 2]) nl += 2;
            if (idx >= s_p[nl + 1]) nl += 1;
            int j = idx - s_p[nl];
            int e = slots[(size_t)(b0 + nl) * CAP + j];

            const float4* p0 = (const float4*)(f0 + (size_t)e * DD);
            const float4* p1 = (const float4*)(f1 + (size_t)e * DD);
            const float4* p2 = (const float4*)(f2 + (size_t)e * DD);
            float4 hv[8];
            {
                float4 v[8]; float ss = 0.f;
                #pragma unroll
                for (int i = 0; i < 8; i++) { v[i] = p0[i];
                    ss += v[i].x*v[i].x + v[i].y*v[i].y + v[i].z*v[i].z + v[i].w*v[i].w; }
                float inv = 1.0f / fmaxf(sqrtf(ss), 1e-12f);
                #pragma unroll
                for (int i = 0; i < 8; i++)
                    hv[i] = make_float4(v[i].x*inv, v[i].y*inv, v[i].z*inv, v[i].w*inv);
            }
            {
                float4 v[8]; float ss = 0.f;
                #pragma unroll
                for (int i = 0; i < 8; i++) { v[i] = p1[i];
                    ss += v[i].x*v[i].x + v[i].y*v[i].y + v[i].z*v[i].z + v[i].w*v[i].w; }
                float inv = 1.0f / fmaxf(sqrtf(ss), 1e-12f);
                #pragma unroll
                for (int i = 0; i < 8; i++) {
                    hv[i].x += v[i].x*inv; hv[i].y += v[i].y*inv;
                    hv[i].z += v[i].z*inv; hv[i].w += v[i].w*inv; }
            }
            {
                float4 v[8]; float ss = 0.f;
                #pragma unroll
                for (int i = 0; i < 8; i++) { v[i] = p2[i];
                    ss += v[i].x*v[i].x + v[i].y*v[i].y + v[i].z*v[i].z + v[i].w*v[i].w; }
                float inv = 1.0f / fmaxf(sqrtf(ss), 1e-12f);
                #pragma unroll
                for (int i = 0; i < 8; i++) {
                    hv[i].x += v[i].x*inv; hv[i].y += v[i].y*inv;
                    hv[i].z += v[i].z*inv; hv[i].w += v[i].w*inv; }
            }
            const float4* R4 = (const float4*)s_R;
            #pragma unroll
            for (int i = 0; i < 8; i++) {
                float4 r = R4[i];
                hv[i].x = (hv[i].x + r.x) * (1.0f/3.0f);
                hv[i].y = (hv[i].y + r.y) * (1.0f/3.0f);
                hv[i].z = (hv[i].z + r.z) * (1.0f/3.0f);
                hv[i].w = (hv[i].w + r.w) * (1.0f/3.0f);
            }
            float ex[HH];
            const float4* A4 = (const float4*)s_att;
            #pragma unroll
            for (int q = 0; q < HH; q++) {
                float a = 0.f;
                #pragma unroll
                for (int i = 0; i < 8; i++) {
                    float4 w = A4[q * 8 + i];
                    a += hv[i].x*w.x + hv[i].y*w.y + hv[i].z*w.z + hv[i].w*w.w;
                }
                a = a > 0.f ? a : ALPHA * a;
                ex[q] = __expf(a);
            }
            float* sl = &s_edge[t * LST];
            float4* sl4 = (float4*)sl;
            #pragma unroll
            for (int i = 0; i < 8; i++) sl4[i] = hv[i];
            sl4[8] = make_float4(ex[0], ex[1], ex[2], ex[3]);
            sl4[9] = make_float4(ex[4], ex[5], ex[6], ex[7]);
        }
        __syncthreads();

        // aggregate owned node A (nl0) and B (nl0+8) over this chunk's window
        {
            int a0 = s_p[nl0] - base, a1 = s_p[nl0 + 1] - base;
            if (a0 < 0) a0 = 0;
            if (a1 > ECH) a1 = ECH;
            for (int s = a0; s < a1; s++) {
                const float* sp = &s_edge[s * LST];
                float h = sp[d];
                #pragma unroll
                for (int q = 0; q < HH; q++) { float x = sp[32 + q]; den0[q] += x; num0[q] += x * h; }
            }
        }
        {
            int a0 = s_p[nl0 + 8] - base, a1 = s_p[nl0 + 9] - base;
            if (a0 < 0) a0 = 0;
            if (a1 > ECH) a1 = ECH;
            for (int s = a0; s < a1; s++) {
                const float* sp = &s_edge[s * LST];
                float h = sp[d];
                #pragma unroll
                for (int q = 0; q < HH; q++) { float x = sp[32 + q]; den1[q] += x; num1[q] += x * h; }
            }
        }
        __syncthreads();
    }

    // exact overflow handling (deg > CAP): scan the (tiny) global overflow list
    int novf = *ovfc;
    if (novf > OVF_MAX) novf = OVF_MAX;
    if (novf > 0) {
        int nA = b0 + nl0;
        if (nA < N && s_rawdeg[nl0] > CAP) {
            for (int k = 0; k < novf; k++) {
                int2 pr = ovf[k];
                if (pr.y != nA) continue;
                float hd, ex[HH];
                ovf_encode(f0, f1, f2, s_R, s_att, pr.x, d, &hd, ex);
                #pragma unroll
                for (int q = 0; q < HH; q++) { den0[q] += ex[q]; num0[q] += ex[q] * hd; }
            }
        }
        int nB = b0 + nl0 + 8;
        if (nB < N && s_rawdeg[nl0 + 8] > CAP) {
            for (int k = 0; k < novf; k++) {
                int2 pr = ovf[k];
                if (pr.y != nB) continue;
                float hd, ex[HH];
                ovf_encode(f0, f1, f2, s_R, s_att, pr.x, d, &hd, ex);
                #pragma unroll
                for (int q = 0; q < HH; q++) { den1[q] += ex[q]; num1[q] += ex[q] * hd; }
            }
        }
    }

    // write out: lanes 0..31 of each group cover consecutive d -> coalesced
    int nA = b0 + nl0;
    if (nA < N) {
        size_t ob = (size_t)nA * (HH * DD) + d;
        #pragma unroll
        for (int q = 0; q < HH; q++) {
            float dv = den0[q];
            out[ob + q * DD] = dv > 0.f ? num0[q] / dv : 0.f;
        }
    }
    int nB = b0 + nl0 + 8;
    if (nB < N) {
        size_t ob = (size_t)nB * (HH * DD) + d;
        #pragma unroll
        for (int q = 0; q < HH; q++) {
            float dv = den1[q];
            out[ob + q * DD] = dv > 0.f ? num1[q] / dv : 0.f;
        }
    }
}

extern "C" void kernel_launch(void* const* d_in, const int* in_sizes, int n_in,
                              void* d_out, int out_size, void* d_ws, size_t ws_size,
                              hipStream_t stream)
{
    const float* f0   = (const float*)d_in[0];
    const float* f1   = (const float*)d_in[1];
    const float* f2   = (const float*)d_in[2];
    const float* rv   = (const float*)d_in[3];
    const float* attn = (const float*)d_in[4];
    const int*   dst  = (const int*)d_in[5];
    int E = in_sizes[0] / DD;
    int N = out_size / (HH * DD);
    float* out = (float*)d_out;

    auto al = [](size_t x) { return (x + 255) & ~(size_t)255; };
    char* w = (char*)d_ws;
    size_t off = 0;
    int*  slots = (int*)(w + off);  off += al((size_t)N * CAP * 4);
    int*  cnt   = (int*)(w + off);  off += al((size_t)N * 4);
    int*  ovfc  = (int*)(w + off);  off += al(256);
    int2* ovf   = (int2*)(w + off); off += al((size_t)OVF_MAX * 8);
    (void)ws_size; (void)n_in;

    k_zero<<<(N + 255) / 256, 256, 0, stream>>>(cnt, ovfc, N);
    k_slot<<<(E + 255) / 256, 256, 0, stream>>>(dst, E, cnt, slots, ovfc, ovf);
    k_fused<<<(N + G - 1) / G, 256, 0, stream>>>(f0, f1, f2, rv, attn, slots, cnt,
                                                 ovfc, ovf, out, N);
}

// Round 17
// 491.334 us; speedup vs baseline: 1.3827x; 1.0680x over previous
//
#include <hip/hip_runtime.h>
#include <hip/hip_fp16.h>

#define DD 32
#define HH 8
#define ALPHA 0.01f
#define CAP 32            // slots per node; overflow handled exactly via ovf list
#define G 16              // nodes per block
#define ECH 256           // edge slots encoded per chunk (== blockDim)
#define LSTW 24           // LDS dwords per edge slot: 32 x half h + 8 x f32 ex = 96B
#define OVF_MAX (1 << 20)

__global__ __launch_bounds__(256) void k_zero(int* __restrict__ cnt, int* __restrict__ ovfc, int N) {
    int i = blockIdx.x * 256 + threadIdx.x;
    if (i < N) cnt[i] = 0;
    if (i == 0) *ovfc = 0;
}

// 4 edges per thread: independent atomics issue back-to-back (ILP hides the
// ~500cy round-trip that serialized the 1-edge-per-thread version).
__global__ __launch_bounds__(256) void k_slot(const int* __restrict__ dst, int E,
                                              int* __restrict__ cnt, int* __restrict__ slots,
                                              int* __restrict__ ovfc, int2* __restrict__ ovf) {
    int t0 = blockIdx.x * 1024 + threadIdx.x;
    int e[4], n[4], r[4];
    #pragma unroll
    for (int k = 0; k < 4; k++) {
        e[k] = t0 + k * 256;                      // coalesced per sub-iteration
        n[k] = (e[k] < E) ? dst[e[k]] : -1;
    }
    #pragma unroll
    for (int k = 0; k < 4; k++)
        if (n[k] >= 0) r[k] = atomicAdd(&cnt[n[k]], 1);
    #pragma unroll
    for (int k = 0; k < 4; k++) {
        if (n[k] < 0) continue;
        if (r[k] < CAP) slots[(size_t)n[k] * CAP + r[k]] = e[k];
        else { int p = atomicAdd(ovfc, 1); if (p < OVF_MAX) ovf[p] = make_int2(e[k], n[k]); }
    }
}

// rare-path full encode for one edge (returns h[d] and ex[8])
__device__ __noinline__ void ovf_encode(const float* __restrict__ f0, const float* __restrict__ f1,
                                        const float* __restrict__ f2, const float* __restrict__ s_R,
                                        const float* __restrict__ s_att, int e, int d,
                                        float* hd, float* ex) {
    float h[DD];
    float s0 = 0.f, s1 = 0.f, s2 = 0.f;
    for (int i = 0; i < DD; i++) {
        float x0 = f0[(size_t)e * DD + i], x1 = f1[(size_t)e * DD + i], x2 = f2[(size_t)e * DD + i];
        s0 += x0 * x0; s1 += x1 * x1; s2 += x2 * x2;
        h[i] = x0;
    }
    float i0 = 1.0f / fmaxf(sqrtf(s0), 1e-12f);
    float i1 = 1.0f / fmaxf(sqrtf(s1), 1e-12f);
    float i2 = 1.0f / fmaxf(sqrtf(s2), 1e-12f);
    for (int i = 0; i < DD; i++) {
        float x1 = f1[(size_t)e * DD + i], x2 = f2[(size_t)e * DD + i];
        h[i] = (h[i] * i0 + x1 * i1 + x2 * i2 + s_R[i]) * (1.0f / 3.0f);
    }
    for (int q = 0; q < HH; q++) {
        float a = 0.f;
        for (int i = 0; i < DD; i++) a += h[i] * s_att[q * DD + i];
        a = a > 0.f ? a : ALPHA * a;
        ex[q] = __expf(a);
    }
    *hd = h[d];
}

// Fused encode+aggregate. Block = 16 nodes. Phase 1: thread-per-edge encode into
// a 96B LDS slot (h as fp16, ex as f32). Phase 2: thread (node,dim) accumulates
// num/den from LDS (u16 h reads 2-way/free; ex via 2 broadcast b128 reads).
__global__ __launch_bounds__(256) void k_fused(
    const float* __restrict__ f0, const float* __restrict__ f1, const float* __restrict__ f2,
    const float* __restrict__ rv, const float* __restrict__ attn,
    const int* __restrict__ slots, const int* __restrict__ cnt,
    const int* __restrict__ ovfc, const int2* __restrict__ ovf,
    float* __restrict__ out, int N)
{
    __shared__ float s_att[HH * DD];          // [q*32+d]
    __shared__ float s_R[DD];
    __shared__ float s_edge[ECH * LSTW];      // 24576 B
    __shared__ int s_p[G + 1];
    __shared__ int s_rawdeg[G];

    int t = threadIdx.x;
    s_att[t] = attn[t];                       // blockDim == HH*DD == 256
    if (t < DD) s_R[t] = rv[t] + 2.0f * (rv[DD + t] + rv[2 * DD + t]);
    int b0 = blockIdx.x * G;
    if (t < G) {
        int n = b0 + t;
        s_rawdeg[t] = (n < N) ? cnt[n] : 0;
    }
    __syncthreads();
    if (t == 0) {
        int a = 0;
        for (int i = 0; i < G; i++) {
            s_p[i] = a;
            int dg = s_rawdeg[i];
            a += (dg < CAP ? dg : CAP);
        }
        s_p[G] = a;
    }
    __syncthreads();
    int total = s_p[G];                       // <= G*CAP = 512 -> at most 2 chunks

    int d = t & 31, nl0 = t >> 5;             // thread owns (node nl0, dim d) and (node nl0+8, dim d)
    float num0[HH], den0[HH], num1[HH], den1[HH];
    #pragma unroll
    for (int q = 0; q < HH; q++) { num0[q] = den0[q] = num1[q] = den1[q] = 0.f; }

    for (int base = 0; base < total; base += ECH) {
        int idx = base + t;
        if (idx < total) {
            // locate (node, j) by binary search over 16-entry prefix
            int nl = 0;
            if (idx >= s_p[nl + 8]) nl += 8;
            if (idx >= s_p[nl + 4]) nl += 4;
            if (idx >= s_p[nl + 2]) nl += 2;
            if (idx >= s_p[nl + 1]) nl += 1;
            int j = idx - s_p[nl];
            int e = slots[(size_t)(b0 + nl) * CAP + j];

            const float4* p0 = (const float4*)(f0 + (size_t)e * DD);
            const float4* p1 = (const float4*)(f1 + (size_t)e * DD);
            const float4* p2 = (const float4*)(f2 + (size_t)e * DD);
            float4 hv[8];
            {
                float4 v[8]; float ss = 0.f;
                #pragma unroll
                for (int i = 0; i < 8; i++) { v[i] = p0[i];
                    ss += v[i].x*v[i].x + v[i].y*v[i].y + v[i].z*v[i].z + v[i].w*v[i].w; }
                float inv = 1.0f / fmaxf(sqrtf(ss), 1e-12f);
                #pragma unroll
                for (int i = 0; i < 8; i++)
                    hv[i] = make_float4(v[i].x*inv, v[i].y*inv, v[i].z*inv, v[i].w*inv);
            }
            {
                float4 v[8]; float ss = 0.f;
                #pragma unroll
                for (int i = 0; i < 8; i++) { v[i] = p1[i];
                    ss += v[i].x*v[i].x + v[i].y*v[i].y + v[i].z*v[i].z + v[i].w*v[i].w; }
                float inv = 1.0f / fmaxf(sqrtf(ss), 1e-12f);
                #pragma unroll
                for (int i = 0; i < 8; i++) {
                    hv[i].x += v[i].x*inv; hv[i].y += v[i].y*inv;
                    hv[i].z += v[i].z*inv; hv[i].w += v[i].w*inv; }
            }
            {
                float4 v[8]; float ss = 0.f;
                #pragma unroll
                for (int i = 0; i < 8; i++) { v[i] = p2[i];
                    ss += v[i].x*v[i].x + v[i].y*v[i].y + v[i].z*v[i].z + v[i].w*v[i].w; }
                float inv = 1.0f / fmaxf(sqrtf(ss), 1e-12f);
                #pragma unroll
                for (int i = 0; i < 8; i++) {
                    hv[i].x += v[i].x*inv; hv[i].y += v[i].y*inv;
                    hv[i].z += v[i].z*inv; hv[i].w += v[i].w*inv; }
            }
            const float4* R4 = (const float4*)s_R;
            #pragma unroll
            for (int i = 0; i < 8; i++) {
                float4 r = R4[i];
                hv[i].x = (hv[i].x + r.x) * (1.0f/3.0f);
                hv[i].y = (hv[i].y + r.y) * (1.0f/3.0f);
                hv[i].z = (hv[i].z + r.z) * (1.0f/3.0f);
                hv[i].w = (hv[i].w + r.w) * (1.0f/3.0f);
            }
            float ex[HH];
            const float4* A4 = (const float4*)s_att;
            #pragma unroll
            for (int q = 0; q < HH; q++) {
                float a = 0.f;
                #pragma unroll
                for (int i = 0; i < 8; i++) {
                    float4 w = A4[q * 8 + i];
                    a += hv[i].x*w.x + hv[i].y*w.y + hv[i].z*w.z + hv[i].w*w.w;
                }
                a = a > 0.f ? a : ALPHA * a;
                ex[q] = __expf(a);
            }
            // pack: h -> fp16 (4 x float4), ex -> f32 (2 x float4); 96B slot
            union PU { __half2 h2[16]; float4 f4[4]; } u;
            #pragma unroll
            for (int i = 0; i < 8; i++) {
                u.h2[2*i]   = __floats2half2_rn(hv[i].x, hv[i].y);
                u.h2[2*i+1] = __floats2half2_rn(hv[i].z, hv[i].w);
            }
            float4* sl4 = (float4*)&s_edge[t * LSTW];
            #pragma unroll
            for (int i = 0; i < 4; i++) sl4[i] = u.f4[i];
            sl4[4] = make_float4(ex[0], ex[1], ex[2], ex[3]);
            sl4[5] = make_float4(ex[4], ex[5], ex[6], ex[7]);
        }
        __syncthreads();

        // aggregate node A (nl0) and B (nl0+8) over this chunk's window
        {
            int a0 = s_p[nl0] - base, a1 = s_p[nl0 + 1] - base;
            if (a0 < 0) a0 = 0;
            if (a1 > ECH) a1 = ECH;
            for (int s = a0; s < a1; s++) {
                const float* sp = &s_edge[s * LSTW];
                float h = __half2float(((const __half*)sp)[d]);
                float4 xa = ((const float4*)sp)[4];
                float4 xb = ((const float4*)sp)[5];
                den0[0] += xa.x; num0[0] += xa.x * h;
                den0[1] += xa.y; num0[1] += xa.y * h;
                den0[2] += xa.z; num0[2] += xa.z * h;
                den0[3] += xa.w; num0[3] += xa.w * h;
                den0[4] += xb.x; num0[4] += xb.x * h;
                den0[5] += xb.y; num0[5] += xb.y * h;
                den0[6] += xb.z; num0[6] += xb.z * h;
                den0[7] += xb.w; num0[7] += xb.w * h;
            }
        }
        {
            int a0 = s_p[nl0 + 8] - base, a1 = s_p[nl0 + 9] - base;
            if (a0 < 0) a0 = 0;
            if (a1 > ECH) a1 = ECH;
            for (int s = a0; s < a1; s++) {
                const float* sp = &s_edge[s * LSTW];
                float h = __half2float(((const __half*)sp)[d]);
                float4 xa = ((const float4*)sp)[4];
                float4 xb = ((const float4*)sp)[5];
                den1[0] += xa.x; num1[0] += xa.x * h;
                den1[1] += xa.y; num1[1] += xa.y * h;
                den1[2] += xa.z; num1[2] += xa.z * h;
                den1[3] += xa.w; num1[3] += xa.w * h;
                den1[4] += xb.x; num1[4] += xb.x * h;
                den1[5] += xb.y; num1[5] += xb.y * h;
                den1[6] += xb.z; num1[6] += xb.z * h;
                den1[7] += xb.w; num1[7] += xb.w * h;
            }
        }
        __syncthreads();
    }

    // exact overflow handling (deg > CAP): scan the (tiny) global overflow list
    int novf = *ovfc;
    if (novf > OVF_MAX) novf = OVF_MAX;
    if (novf > 0) {
        int nA = b0 + nl0;
        if (nA < N && s_rawdeg[nl0] > CAP) {
            for (int k = 0; k < novf; k++) {
                int2 pr = ovf[k];
                if (pr.y != nA) continue;
                float hd, ex[HH];
                ovf_encode(f0, f1, f2, s_R, s_att, pr.x, d, &hd, ex);
                #pragma unroll
                for (int q = 0; q < HH; q++) { den0[q] += ex[q]; num0[q] += ex[q] * hd; }
            }
        }
        int nB = b0 + nl0 + 8;
        if (nB < N && s_rawdeg[nl0 + 8] > CAP) {
            for (int k = 0; k < novf; k++) {
                int2 pr = ovf[k];
                if (pr.y != nB) continue;
                float hd, ex[HH];
                ovf_encode(f0, f1, f2, s_R, s_att, pr.x, d, &hd, ex);
                #pragma unroll
                for (int q = 0; q < HH; q++) { den1[q] += ex[q]; num1[q] += ex[q] * hd; }
            }
        }
    }

    // write out: lanes 0..31 of each group cover consecutive d -> coalesced
    int nA = b0 + nl0;
    if (nA < N) {
        size_t ob = (size_t)nA * (HH * DD) + d;
        #pragma unroll
        for (int q = 0; q < HH; q++) {
            float dv = den0[q];
            out[ob + q * DD] = dv > 0.f ? num0[q] / dv : 0.f;
        }
    }
    int nB = b0 + nl0 + 8;
    if (nB < N) {
        size_t ob = (size_t)nB * (HH * DD) + d;
        #pragma unroll
        for (int q = 0; q < HH; q++) {
            float dv = den1[q];
            out[ob + q * DD] = dv > 0.f ? num1[q] / dv : 0.f;
        }
    }
}

extern "C" void kernel_launch(void* const* d_in, const int* in_sizes, int n_in,
                              void* d_out, int out_size, void* d_ws, size_t ws_size,
                              hipStream_t stream)
{
    const float* f0   = (const float*)d_in[0];
    const float* f1   = (const float*)d_in[1];
    const float* f2   = (const float*)d_in[2];
    const float* rv   = (const float*)d_in[3];
    const float* attn = (const float*)d_in[4];
    const int*   dst  = (const int*)d_in[5];
    int E = in_sizes[0] / DD;
    int N = out_size / (HH * DD);
    float* out = (float*)d_out;

    auto al = [](size_t x) { return (x + 255) & ~(size_t)255; };
    char* w = (char*)d_ws;
    size_t off = 0;
    int*  slots = (int*)(w + off);  off += al((size_t)N * CAP * 4);
    int*  cnt   = (int*)(w + off);  off += al((size_t)N * 4);
    int*  ovfc  = (int*)(w + off);  off += al(256);
    int2* ovf   = (int2*)(w + off); off += al((size_t)OVF_MAX * 8);
    (void)ws_size; (void)n_in;

    k_zero<<<(N + 255) / 256, 256, 0, stream>>>(cnt, ovfc, N);
    k_slot<<<(E + 1023) / 1024, 256, 0, stream>>>(dst, E, cnt, slots, ovfc, ovf);
    k_fused<<<(N + G - 1) / G, 256, 0, stream>>>(f0, f1, f2, rv, attn, slots, cnt,
                                                 ovfc, ovf, out, N);
}